// Round 3
// baseline (1770.701 us; speedup 1.0000x reference)
//
#include <hip/hip_runtime.h>

// RNN: B=512, T=1024, I=64, H=128, fp32 in/out.
// Round-6: MFMA recurrence with ZERO-communication step relayout.
//  - One wave = one chain of 16 rows (N=16 of mfma_f32_16x16x32_f16).
//    32 blocks x 64 threads; no LDS, no barriers, no shfl in the chain.
//  - Verified D layout (m89/m91): n=l&15, m=16T+4(l>>4)+r. A and B both
//    use l&15 for their non-K index and share k-map kappa(g,j). Packing
//    BOTH A (weights) and B (x,h) with the same bijection
//    phi(g,j)=16(j>>2)+4g+(j&3) keeps the contraction exact without
//    knowing kappa, AND makes next-step B-frags equal (register-for-
//    register) to pk(tanh(acc)) -- no cross-lane movement at all.
//  - Weights W_hh (128 dw) + W_ih (64 dw) + bias (32) live in unified
//    VGPR/AGPR file; MFMA reads AGPR operands directly on gfx950.
//    launch_bounds(64,1) -> 512-reg budget, no spill expected (~320).
//  - x prefetched 2 steps ahead (ping-pong xA/xB), h-independent.
// Precision: f16 operands, fp32 MFMA accum == dot2 numerics class.

#define Bsz 512
#define Tt  1024
#define Ii  64
#define Hh  128
constexpr int NT = 64;     // one wave per block
constexpr int RW = 16;     // rows per wave (= MFMA N)

typedef _Float16 f16x2 __attribute__((ext_vector_type(2)));
typedef _Float16 f16x8 __attribute__((ext_vector_type(8)));
typedef float    f32x4 __attribute__((ext_vector_type(4)));

union F8 { f16x8 v; f16x2 h[4]; };

__device__ __forceinline__ float fast_tanh(float x) {
    float t = __builtin_amdgcn_exp2f(x * 2.8853900817779268f);
    return 1.0f - 2.0f * __builtin_amdgcn_rcpf(t + 1.0f);
}
__device__ __forceinline__ float fast_sigmoid(float z) {
    float t = __builtin_amdgcn_exp2f(-z * 1.4426950408889634f);
    return __builtin_amdgcn_rcpf(1.0f + t);
}
// round-to-zero packed f32->f16x2 (1 inst) for dynamic values
__device__ __forceinline__ f16x2 pk(float a, float b) {
    return (f16x2)__builtin_amdgcn_cvt_pkrtz(a, b);
}
// RTN pair for one-time weight conversion
__device__ __forceinline__ f16x2 pkw(float a, float b) {
    f16x2 r; r[0] = (_Float16)a; r[1] = (_Float16)b; return r;
}

__global__ __launch_bounds__(NT, 1)
void rnn_mfma(const float* __restrict__ x,
              const float* __restrict__ W_ih,
              const float* __restrict__ W_hh,
              const float* __restrict__ b_ih,
              const float* __restrict__ b_hh,
              const float* __restrict__ fc_w,
              const float* __restrict__ fc_b,
              float* __restrict__ out)
{
    const int l  = threadIdx.x;
    const int n  = l & 15;          // row-within-group (MFMA N index)
    const int g  = l >> 4;          // lane group (K sub-index)
    const int rb = blockIdx.x * RW;

    // ---- A-frags: W_hh [Mtile 8][Ktile 4], phi-packed k order ----
    F8 whh[8][4];
    #pragma unroll
    for (int T = 0; T < 8; ++T) {
        const float* wr = W_hh + (size_t)(16 * T + n) * Hh;
        #pragma unroll
        for (int q = 0; q < 4; ++q) {
            float4 a = *(const float4*)(wr + 32 * q + 4 * g);
            float4 b = *(const float4*)(wr + 32 * q + 16 + 4 * g);
            whh[T][q].h[0] = pkw(a.x, a.y);
            whh[T][q].h[1] = pkw(a.z, a.w);
            whh[T][q].h[2] = pkw(b.x, b.y);
            whh[T][q].h[3] = pkw(b.z, b.w);
        }
    }
    // ---- A-frags: W_ih [Mtile 8][Ktile 2] ----
    F8 wih[8][2];
    #pragma unroll
    for (int T = 0; T < 8; ++T) {
        const float* wr = W_ih + (size_t)(16 * T + n) * Ii;
        #pragma unroll
        for (int q = 0; q < 2; ++q) {
            float4 a = *(const float4*)(wr + 32 * q + 4 * g);
            float4 b = *(const float4*)(wr + 32 * q + 16 + 4 * g);
            wih[T][q].h[0] = pkw(a.x, a.y);
            wih[T][q].h[1] = pkw(a.z, a.w);
            wih[T][q].h[2] = pkw(b.x, b.y);
            wih[T][q].h[3] = pkw(b.z, b.w);
        }
    }
    // ---- bias in D layout: element r of tile T = b[16T+4g+r] ----
    f32x4 biasc[8];
    #pragma unroll
    for (int T = 0; T < 8; ++T) {
        float4 u = *(const float4*)(b_ih + 16 * T + 4 * g);
        float4 v = *(const float4*)(b_hh + 16 * T + 4 * g);
        biasc[T][0] = u.x + v.x; biasc[T][1] = u.y + v.y;
        biasc[T][2] = u.z + v.z; biasc[T][3] = u.w + v.w;
    }

    // ---- h0 = 0 B-frags ----
    F8 hb[4];
    #pragma unroll
    for (int q = 0; q < 4; ++q) {
        hb[q].h[0] = (f16x2)0; hb[q].h[1] = (f16x2)0;
        hb[q].h[2] = (f16x2)0; hb[q].h[3] = (f16x2)0;
    }

    // ---- x prefetch, distance 2 (ping-pong) ----
    const float* xrow = x + (size_t)(rb + n) * Tt * Ii;
    float4 xA[4], xB[4];
    #pragma unroll
    for (int i = 0; i < 4; ++i) {
        xA[i] = ((const float4*)(xrow + 0 * Ii))[4 * i + g];
        xB[i] = ((const float4*)(xrow + 1 * Ii))[4 * i + g];
    }

#define STEP(tcur, XR)                                                        \
  {                                                                           \
    F8 xb0, xb1;                                                              \
    xb0.h[0] = pk(XR[0].x, XR[0].y); xb0.h[1] = pk(XR[0].z, XR[0].w);         \
    xb0.h[2] = pk(XR[1].x, XR[1].y); xb0.h[3] = pk(XR[1].z, XR[1].w);         \
    xb1.h[0] = pk(XR[2].x, XR[2].y); xb1.h[1] = pk(XR[2].z, XR[2].w);         \
    xb1.h[2] = pk(XR[3].x, XR[3].y); xb1.h[3] = pk(XR[3].z, XR[3].w);         \
    const int tl = ((tcur) + 2 < Tt) ? (tcur) + 2 : Tt - 1;                   \
    const float4* xpre = (const float4*)(xrow + (size_t)tl * Ii);             \
    _Pragma("unroll")                                                         \
    for (int i = 0; i < 4; ++i) XR[i] = xpre[4 * i + g];                      \
    f32x4 acc[8];                                                             \
    _Pragma("unroll")                                                         \
    for (int T = 0; T < 8; ++T) {                                             \
        acc[T] = __builtin_amdgcn_mfma_f32_16x16x32_f16(wih[T][0].v, xb0.v,   \
                                                        biasc[T], 0, 0, 0);   \
        acc[T] = __builtin_amdgcn_mfma_f32_16x16x32_f16(wih[T][1].v, xb1.v,   \
                                                        acc[T], 0, 0, 0);     \
        _Pragma("unroll")                                                     \
        for (int q = 0; q < 4; ++q)                                           \
            acc[T] = __builtin_amdgcn_mfma_f32_16x16x32_f16(whh[T][q].v,      \
                                                    hb[q].v, acc[T], 0, 0, 0);\
    }                                                                         \
    _Pragma("unroll")                                                         \
    for (int q = 0; q < 4; ++q) {                                             \
        hb[q].h[0] = pk(fast_tanh(acc[2*q][0]),   fast_tanh(acc[2*q][1]));    \
        hb[q].h[1] = pk(fast_tanh(acc[2*q][2]),   fast_tanh(acc[2*q][3]));    \
        hb[q].h[2] = pk(fast_tanh(acc[2*q+1][0]), fast_tanh(acc[2*q+1][1]));  \
        hb[q].h[3] = pk(fast_tanh(acc[2*q+1][2]), fast_tanh(acc[2*q+1][3]));  \
    }                                                                         \
  }

    for (int t = 0; t < Tt; t += 2) {
        STEP(t,     xA)
        STEP(t + 1, xB)
    }
#undef STEP

    // ---- epilogue: out[n] = sigmoid(fc_b + sum_m fc_w[m] h[m][n]) ----
    // lane holds h[phi(g,j)+32q][n] in hb; fc_w loaded with same phi.
    float partial = 0.0f;
    #pragma unroll
    for (int q = 0; q < 4; ++q) {
        float4 fa = *(const float4*)(fc_w + 32 * q + 4 * g);
        float4 fb = *(const float4*)(fc_w + 32 * q + 16 + 4 * g);
        partial += fa.x * (float)hb[q].h[0][0];
        partial += fa.y * (float)hb[q].h[0][1];
        partial += fa.z * (float)hb[q].h[1][0];
        partial += fa.w * (float)hb[q].h[1][1];
        partial += fb.x * (float)hb[q].h[2][0];
        partial += fb.y * (float)hb[q].h[2][1];
        partial += fb.z * (float)hb[q].h[3][0];
        partial += fb.w * (float)hb[q].h[3][1];
    }
    // reduce the 4 lane-groups holding the same n: lanes n, n+16, n+32, n+48
    partial += __shfl_xor(partial, 16, 64);
    partial += __shfl_xor(partial, 32, 64);
    if (l < 16) out[rb + l] = fast_sigmoid(fc_b[0] + partial);
}

extern "C" void kernel_launch(void* const* d_in, const int* in_sizes, int n_in,
                              void* d_out, int out_size, void* d_ws, size_t ws_size,
                              hipStream_t stream) {
    const float* x    = (const float*)d_in[0];
    const float* W_ih = (const float*)d_in[1];
    const float* W_hh = (const float*)d_in[2];
    const float* b_ih = (const float*)d_in[3];
    const float* b_hh = (const float*)d_in[4];
    const float* fc_w = (const float*)d_in[5];
    const float* fc_b = (const float*)d_in[6];
    float* out = (float*)d_out;

    rnn_mfma<<<Bsz / RW, NT, 0, stream>>>(x, W_ih, W_hh, b_ih, b_hh, fc_w, fc_b, out);
}

// Round 4
// 1288.020 us; speedup vs baseline: 1.3747x; 1.3747x over previous
//
#include <hip/hip_runtime.h>

// RNN: B=512, T=1024, I=64, H=128, fp32 in/out.
// Round-7: MFMA zero-communication recurrence (verified in round-6),
// restructured for latency:
//  - 4-step register load ring (static indices), loads issued 4 steps
//    ahead -> ~3 step-times of slack vs ~900cy HBM latency. Peeled
//    prologue/drain keep the hot loop free of clamps and vmcnt(0) collapse.
//  - K-chain split: per T-tile two independent depth-2 MFMA chains
//    ((bias+x)->hh0->hh1 || 0->hh2->hh3) + one f32x4 add. Was 6-deep.
//  - x-projection of step t+1 (16 MFMAs, h-independent) issues in step
//    t's h-MFMA shadow, ping-ponged xaccA/xaccB.
//  - One wave per block, 32 blocks (16 rows/wave); no LDS, no barriers,
//    no cross-lane ops in the chain. launch_bounds(64,1): 512-reg budget.
// Precision: f16 operands, fp32 MFMA accum (same class as round-0 dot2).

#define Bsz 512
#define Tt  1024
#define Ii  64
#define Hh  128
constexpr int NT = 64;     // one wave per block
constexpr int RW = 16;     // rows per wave (= MFMA N)

typedef _Float16 f16x2 __attribute__((ext_vector_type(2)));
typedef _Float16 f16x8 __attribute__((ext_vector_type(8)));
typedef float    f32x4 __attribute__((ext_vector_type(4)));

union F8 { f16x8 v; f16x2 h[4]; };

__device__ __forceinline__ float fast_tanh(float x) {
    float t = __builtin_amdgcn_exp2f(x * 2.8853900817779268f);
    return 1.0f - 2.0f * __builtin_amdgcn_rcpf(t + 1.0f);
}
__device__ __forceinline__ float fast_sigmoid(float z) {
    float t = __builtin_amdgcn_exp2f(-z * 1.4426950408889634f);
    return __builtin_amdgcn_rcpf(1.0f + t);
}
__device__ __forceinline__ f16x2 pk(float a, float b) {
    return (f16x2)__builtin_amdgcn_cvt_pkrtz(a, b);
}
__device__ __forceinline__ f16x2 pkw(float a, float b) {
    f16x2 r; r[0] = (_Float16)a; r[1] = (_Float16)b; return r;
}

__global__ __launch_bounds__(NT, 1)
void rnn_mfma2(const float* __restrict__ x,
               const float* __restrict__ W_ih,
               const float* __restrict__ W_hh,
               const float* __restrict__ b_ih,
               const float* __restrict__ b_hh,
               const float* __restrict__ fc_w,
               const float* __restrict__ fc_b,
               float* __restrict__ out)
{
    const int l  = threadIdx.x;
    const int n  = l & 15;          // MFMA N index (row within group)
    const int g  = l >> 4;          // lane group (K sub-index)
    const int rb = blockIdx.x * RW;

    // ---- A-frags: W_hh [Mtile 8][Ktile 4], phi-packed (round-6 verified) ----
    F8 whh[8][4];
    #pragma unroll
    for (int T = 0; T < 8; ++T) {
        const float* wr = W_hh + (size_t)(16 * T + n) * Hh;
        #pragma unroll
        for (int q = 0; q < 4; ++q) {
            float4 a = *(const float4*)(wr + 32 * q + 4 * g);
            float4 b = *(const float4*)(wr + 32 * q + 16 + 4 * g);
            whh[T][q].h[0] = pkw(a.x, a.y);
            whh[T][q].h[1] = pkw(a.z, a.w);
            whh[T][q].h[2] = pkw(b.x, b.y);
            whh[T][q].h[3] = pkw(b.z, b.w);
        }
    }
    // ---- A-frags: W_ih [Mtile 8][Ktile 2] ----
    F8 wih[8][2];
    #pragma unroll
    for (int T = 0; T < 8; ++T) {
        const float* wr = W_ih + (size_t)(16 * T + n) * Ii;
        #pragma unroll
        for (int q = 0; q < 2; ++q) {
            float4 a = *(const float4*)(wr + 32 * q + 4 * g);
            float4 b = *(const float4*)(wr + 32 * q + 16 + 4 * g);
            wih[T][q].h[0] = pkw(a.x, a.y);
            wih[T][q].h[1] = pkw(a.z, a.w);
            wih[T][q].h[2] = pkw(b.x, b.y);
            wih[T][q].h[3] = pkw(b.z, b.w);
        }
    }
    // ---- bias in D layout: element r of tile T = b[16T+4g+r] ----
    f32x4 biasc[8];
    #pragma unroll
    for (int T = 0; T < 8; ++T) {
        float4 u = *(const float4*)(b_ih + 16 * T + 4 * g);
        float4 v = *(const float4*)(b_hh + 16 * T + 4 * g);
        biasc[T][0] = u.x + v.x; biasc[T][1] = u.y + v.y;
        biasc[T][2] = u.z + v.z; biasc[T][3] = u.w + v.w;
    }

    // ---- h0 = 0 B-frags ----
    F8 hb[4];
    #pragma unroll
    for (int q = 0; q < 4; ++q) {
        hb[q].h[0] = (f16x2)0; hb[q].h[1] = (f16x2)0;
        hb[q].h[2] = (f16x2)0; hb[q].h[3] = (f16x2)0;
    }

    const f32x4 zero4 = {0.f, 0.f, 0.f, 0.f};

    // ---- 4-step x load ring (64 VGPRs), statically indexed ----
    const float4* xr4 = (const float4*)(x + (size_t)(rb + n) * Tt * Ii);
    float4 ring[4][4];
    #pragma unroll
    for (int s = 0; s < 4; ++s)
        #pragma unroll
        for (int i = 0; i < 4; ++i)
            ring[s][i] = xr4[s * (Ii / 4) + 4 * i + g];

    f32x4 xaccA[8], xaccB[8];

    // x-projection for step t from ring slot SLOT -> OUT (h-independent)
#define XPROJ(OUT, SLOT)                                                      \
  { F8 xb0, xb1;                                                              \
    xb0.h[0] = pk(ring[SLOT][0].x, ring[SLOT][0].y);                          \
    xb0.h[1] = pk(ring[SLOT][0].z, ring[SLOT][0].w);                          \
    xb0.h[2] = pk(ring[SLOT][1].x, ring[SLOT][1].y);                          \
    xb0.h[3] = pk(ring[SLOT][1].z, ring[SLOT][1].w);                          \
    xb1.h[0] = pk(ring[SLOT][2].x, ring[SLOT][2].y);                          \
    xb1.h[1] = pk(ring[SLOT][2].z, ring[SLOT][2].w);                          \
    xb1.h[2] = pk(ring[SLOT][3].x, ring[SLOT][3].y);                          \
    xb1.h[3] = pk(ring[SLOT][3].z, ring[SLOT][3].w);                          \
    _Pragma("unroll")                                                         \
    for (int T = 0; T < 8; ++T) {                                             \
        OUT[T] = __builtin_amdgcn_mfma_f32_16x16x32_f16(wih[T][0].v, xb0.v,   \
                                                        biasc[T], 0, 0, 0);   \
        OUT[T] = __builtin_amdgcn_mfma_f32_16x16x32_f16(wih[T][1].v, xb1.v,   \
                                                        OUT[T], 0, 0, 0);     \
    } }

    // One recurrence step. XIN holds bias + x-projection for this step.
    // LSLOT gets the load for step TLOAD (4 ahead); CSLOT (x of step t+1)
    // feeds XOUT. DOLOAD/DONEXT are compile-time flags.
#define STEP(XIN, XOUT, LSLOT, CSLOT, DOLOAD, DONEXT, TLOAD)                  \
  {                                                                           \
    if (DOLOAD) {                                                             \
        _Pragma("unroll")                                                     \
        for (int i = 0; i < 4; ++i)                                           \
            ring[LSLOT][i] = xr4[(TLOAD) * (Ii / 4) + 4 * i + g];             \
    }                                                                         \
    f32x4 acc[8];                                                             \
    _Pragma("unroll")                                                         \
    for (int T = 0; T < 8; ++T) {                                             \
        f32x4 cA = __builtin_amdgcn_mfma_f32_16x16x32_f16(whh[T][0].v,        \
                                                hb[0].v, XIN[T], 0, 0, 0);    \
        cA = __builtin_amdgcn_mfma_f32_16x16x32_f16(whh[T][1].v,              \
                                                hb[1].v, cA, 0, 0, 0);        \
        f32x4 cB = __builtin_amdgcn_mfma_f32_16x16x32_f16(whh[T][2].v,        \
                                                hb[2].v, zero4, 0, 0, 0);     \
        cB = __builtin_amdgcn_mfma_f32_16x16x32_f16(whh[T][3].v,              \
                                                hb[3].v, cB, 0, 0, 0);        \
        acc[T] = cA + cB;                                                     \
    }                                                                         \
    if (DONEXT) XPROJ(XOUT, CSLOT);                                           \
    _Pragma("unroll")                                                         \
    for (int q = 0; q < 4; ++q) {                                             \
        hb[q].h[0] = pk(fast_tanh(acc[2*q][0]),   fast_tanh(acc[2*q][1]));    \
        hb[q].h[1] = pk(fast_tanh(acc[2*q][2]),   fast_tanh(acc[2*q][3]));    \
        hb[q].h[2] = pk(fast_tanh(acc[2*q+1][0]), fast_tanh(acc[2*q+1][1]));  \
        hb[q].h[3] = pk(fast_tanh(acc[2*q+1][2]), fast_tanh(acc[2*q+1][3]));  \
    }                                                                         \
  }

    XPROJ(xaccA, 0);                         // x-projection for step 0

    #pragma unroll 1
    for (int t0 = 0; t0 < Tt - 4; t0 += 4) {
        STEP(xaccA, xaccB, 0, 1, 1, 1, t0 + 4)
        STEP(xaccB, xaccA, 1, 2, 1, 1, t0 + 5)
        STEP(xaccA, xaccB, 2, 3, 1, 1, t0 + 6)
        STEP(xaccB, xaccA, 3, 0, 1, 1, t0 + 7)
    }
    // drain: ring slots 0..3 hold x[Tt-4..Tt-1]; xaccA holds proj(x[Tt-4])
    STEP(xaccA, xaccB, 0, 1, 0, 1, 0)
    STEP(xaccB, xaccA, 0, 2, 0, 1, 0)
    STEP(xaccA, xaccB, 0, 3, 0, 1, 0)
    STEP(xaccB, xaccA, 0, 0, 0, 0, 0)

#undef STEP
#undef XPROJ

    // ---- epilogue: out[n] = sigmoid(fc_b + sum_m fc_w[m] h[m][n]) ----
    float partial = 0.0f;
    #pragma unroll
    for (int q = 0; q < 4; ++q) {
        float4 fa = *(const float4*)(fc_w + 32 * q + 4 * g);
        float4 fb = *(const float4*)(fc_w + 32 * q + 16 + 4 * g);
        partial += fa.x * (float)hb[q].h[0][0];
        partial += fa.y * (float)hb[q].h[0][1];
        partial += fa.z * (float)hb[q].h[1][0];
        partial += fa.w * (float)hb[q].h[1][1];
        partial += fb.x * (float)hb[q].h[2][0];
        partial += fb.y * (float)hb[q].h[2][1];
        partial += fb.z * (float)hb[q].h[3][0];
        partial += fb.w * (float)hb[q].h[3][1];
    }
    partial += __shfl_xor(partial, 16, 64);
    partial += __shfl_xor(partial, 32, 64);
    if (l < 16) out[rb + l] = fast_sigmoid(fc_b[0] + partial);
}

extern "C" void kernel_launch(void* const* d_in, const int* in_sizes, int n_in,
                              void* d_out, int out_size, void* d_ws, size_t ws_size,
                              hipStream_t stream) {
    const float* x    = (const float*)d_in[0];
    const float* W_ih = (const float*)d_in[1];
    const float* W_hh = (const float*)d_in[2];
    const float* b_ih = (const float*)d_in[3];
    const float* b_hh = (const float*)d_in[4];
    const float* fc_w = (const float*)d_in[5];
    const float* fc_b = (const float*)d_in[6];
    float* out = (float*)d_out;

    rnn_mfma2<<<Bsz / RW, NT, 0, stream>>>(x, W_ih, W_hh, b_ih, b_hh, fc_w, fc_b, out);
}